// Round 1
// baseline (653.220 us; speedup 1.0000x reference)
//
#include <hip/hip_runtime.h>
#include <hip/hip_bf16.h>
#include <stdint.h>

#define IN_CH 128

// ---------------------------------------------------------------- degree count
__global__ void k_count(const int* __restrict__ dst, int* __restrict__ deg, int E) {
    int e = blockIdx.x * blockDim.x + threadIdx.x;
    if (e < E) atomicAdd(&deg[dst[e]], 1);
}

// ------------------------------------------------- scan stage 1: per-block scan
// block = 256 threads, each thread handles 4 consecutive elements (chunk = 1024)
__global__ void k_scan1(const int* __restrict__ deg, int* __restrict__ row_ptr,
                        int* __restrict__ bsums, int N) {
    __shared__ int ssum[256];
    int tid = threadIdx.x;
    int base = blockIdx.x * 1024 + tid * 4;
    int v0 = 0, v1 = 0, v2 = 0, v3 = 0;
    if (base + 3 < N) {
        int4 q = *(const int4*)(deg + base);
        v0 = q.x; v1 = q.y; v2 = q.z; v3 = q.w;
    } else {
        if (base + 0 < N) v0 = deg[base + 0];
        if (base + 1 < N) v1 = deg[base + 1];
        if (base + 2 < N) v2 = deg[base + 2];
        if (base + 3 < N) v3 = deg[base + 3];
    }
    int ts = v0 + v1 + v2 + v3;
    ssum[tid] = ts;
    __syncthreads();
    // Hillis-Steele inclusive scan over 256 thread sums
    for (int off = 1; off < 256; off <<= 1) {
        int val = (tid >= off) ? ssum[tid - off] : 0;
        __syncthreads();
        ssum[tid] += val;
        __syncthreads();
    }
    int incl = ssum[tid];
    int excl = incl - ts;
    if (base + 0 < N) row_ptr[base + 0] = excl;
    if (base + 1 < N) row_ptr[base + 1] = excl + v0;
    if (base + 2 < N) row_ptr[base + 2] = excl + v0 + v1;
    if (base + 3 < N) row_ptr[base + 3] = excl + v0 + v1 + v2;
    if (tid == 255) bsums[blockIdx.x] = incl;
}

// ---------------------------------------- scan stage 2: scan block sums (NB<=256)
__global__ void k_scan2(int* __restrict__ bsums, int NB) {
    __shared__ int s[256];
    int tid = threadIdx.x;
    s[tid] = (tid < NB) ? bsums[tid] : 0;
    __syncthreads();
    if (tid == 0) {
        int run = 0;
        for (int i = 0; i < NB; i++) { int v = s[i]; s[i] = run; run += v; }
    }
    __syncthreads();
    if (tid < NB) bsums[tid] = s[tid];
}

// ------------------------- scan stage 3: add block offsets, init fill cursors
__global__ void k_scan3(int* __restrict__ row_ptr, int* __restrict__ fill,
                        const int* __restrict__ bsums, int N, int E) {
    int i = blockIdx.x * blockDim.x + threadIdx.x;
    if (i < N) {
        int v = row_ptr[i] + bsums[i >> 10];
        row_ptr[i] = v;
        fill[i] = v;
    }
    if (i == 0) row_ptr[N] = E;
}

// --------------------------------------------------- scatter edges into CSR col
__global__ void k_scatter(const int* __restrict__ src, const int* __restrict__ dst,
                          int* __restrict__ fill, int* __restrict__ col, int E) {
    int e = blockIdx.x * blockDim.x + threadIdx.x;
    if (e < E) {
        int p = atomicAdd(&fill[dst[e]], 1);
        col[p] = src[e];
    }
}

// --------------------------------------------- mean aggregation: 1 wave per node
// lane handles channels {2*lane, 2*lane+1} as float2
__global__ void k_agg(const int* __restrict__ row_ptr, const int* __restrict__ col,
                      const float* __restrict__ X, float* __restrict__ mean, int N) {
    int node = blockIdx.x * (blockDim.x >> 6) + (threadIdx.x >> 6);
    int lane = threadIdx.x & 63;
    if (node >= N) return;
    int s0 = row_ptr[node], s1 = row_ptr[node + 1];
    float ax = 0.f, ay = 0.f;
    int j = s0;
    for (; j + 3 < s1; j += 4) {
        int c0 = col[j], c1 = col[j + 1], c2 = col[j + 2], c3 = col[j + 3];
        float2 a0 = *(const float2*)(X + (size_t)c0 * IN_CH + 2 * lane);
        float2 a1 = *(const float2*)(X + (size_t)c1 * IN_CH + 2 * lane);
        float2 a2 = *(const float2*)(X + (size_t)c2 * IN_CH + 2 * lane);
        float2 a3 = *(const float2*)(X + (size_t)c3 * IN_CH + 2 * lane);
        ax += a0.x + a1.x + a2.x + a3.x;
        ay += a0.y + a1.y + a2.y + a3.y;
    }
    for (; j < s1; j++) {
        float2 a = *(const float2*)(X + (size_t)col[j] * IN_CH + 2 * lane);
        ax += a.x; ay += a.y;
    }
    int degn = s1 - s0;
    float inv = (degn > 0) ? 1.0f / (float)degn : 0.0f;
    float2 r; r.x = ax * inv; r.y = ay * inv;
    *(float2*)(mean + (size_t)node * IN_CH + 2 * lane) = r;
}

// ------------------------------------------------------------- fused dual GEMM
// out[N,BN] = A0 @ W0.T + A1 @ W1.T + bias  (optionally ReLU)
// A0,A1: [N,128] row-major; W0,W1: [BN,128] row-major.
// Treated as K=256 GEMM: k<128 -> (A0,W0), k>=128 -> (A1,W1).
// BM=64 rows/block, BK=32 panel, 256 threads, thread tile 4 x (BN/16).
template <int BN>
__global__ __launch_bounds__(256) void k_gemm(
    const float* __restrict__ A0, const float* __restrict__ A1,
    const float* __restrict__ W0, const float* __restrict__ W1,
    const float* __restrict__ bias, float* __restrict__ out,
    int N, int relu) {
    const int BM = 64, BK = 32;
    const int TN = BN / 16;
    __shared__ float As[BK][BM + 4];
    __shared__ float Ws[BK][BN + 4];

    int tid = threadIdx.x;
    int row0 = blockIdx.x * BM;
    int tr = tid >> 4;   // 0..15 -> rows tr*4 .. tr*4+3
    int tc = tid & 15;   // 0..15 -> cols tc*TN .. tc*TN+TN-1

    float acc[4][TN];
#pragma unroll
    for (int i = 0; i < 4; i++)
#pragma unroll
        for (int j = 0; j < TN; j++) acc[i][j] = 0.f;

    for (int kt = 0; kt < 8; kt++) {
        const float* Ap = (kt < 4) ? A0 : A1;
        const float* Wp = (kt < 4) ? W0 : W1;
        int koff = (kt & 3) * 32;
        __syncthreads();
        // A tile: 64 rows x 32 k = 512 float4-tasks of 4 floats -> 2 per thread
#pragma unroll
        for (int t = 0; t < 2; t++) {
            int task = tid + t * 256;
            int r = task >> 3;
            int kq = (task & 7) * 4;
            int row = row0 + r;
            if (row >= N) row = N - 1;  // clamp; result discarded by store guard
            float4 v = *(const float4*)(Ap + (size_t)row * IN_CH + koff + kq);
            As[kq + 0][r] = v.x; As[kq + 1][r] = v.y;
            As[kq + 2][r] = v.z; As[kq + 3][r] = v.w;
        }
        // W tile: BN cols x 32 k -> BN*8 float4-tasks
#pragma unroll
        for (int t = 0; t < BN / 32; t++) {
            int task = tid + t * 256;
            int c = task >> 3;
            int kq = (task & 7) * 4;
            float4 v = *(const float4*)(Wp + (size_t)c * IN_CH + koff + kq);
            Ws[kq + 0][c] = v.x; Ws[kq + 1][c] = v.y;
            Ws[kq + 2][c] = v.z; Ws[kq + 3][c] = v.w;
        }
        __syncthreads();
#pragma unroll
        for (int kk = 0; kk < BK; kk++) {
            float4 a = *(const float4*)&As[kk][tr * 4];
            float b[TN];
#pragma unroll
            for (int j = 0; j < TN; j++) b[j] = Ws[kk][tc * TN + j];
#pragma unroll
            for (int j = 0; j < TN; j++) {
                acc[0][j] += a.x * b[j];
                acc[1][j] += a.y * b[j];
                acc[2][j] += a.z * b[j];
                acc[3][j] += a.w * b[j];
            }
        }
    }
    // epilogue
#pragma unroll
    for (int i = 0; i < 4; i++) {
        int row = row0 + tr * 4 + i;
        if (row < N) {
#pragma unroll
            for (int j = 0; j < TN; j++) {
                int c = tc * TN + j;
                float v = acc[i][j] + bias[c];
                if (relu) v = fmaxf(v, 0.f);
                out[(size_t)row * BN + c] = v;
            }
        }
    }
}

extern "C" void kernel_launch(void* const* d_in, const int* in_sizes, int n_in,
                              void* d_out, int out_size, void* d_ws, size_t ws_size,
                              hipStream_t stream) {
    const float* x   = (const float*)d_in[0];
    const int* ei    = (const int*)d_in[1];
    const float* Wl1 = (const float*)d_in[2];
    const float* bl1 = (const float*)d_in[3];
    const float* Wr1 = (const float*)d_in[4];
    const float* Wl2 = (const float*)d_in[5];
    const float* bl2 = (const float*)d_in[6];
    const float* Wr2 = (const float*)d_in[7];

    const int N = in_sizes[0] / IN_CH;   // 100000
    const int E = in_sizes[1] / 2;       // 1600000
    const int* src = ei;
    const int* dst = ei + E;

    // workspace carve (256B aligned)
    char* p = (char*)d_ws;
    auto carve = [&](size_t bytes) -> void* {
        void* q = (void*)p;
        p += (bytes + 255) & ~(size_t)255;
        return q;
    };
    int* deg     = (int*)carve((size_t)N * 4);
    int* row_ptr = (int*)carve((size_t)(N + 1) * 4);
    int* fill    = (int*)carve((size_t)N * 4);
    int* bsums   = (int*)carve(1024);
    int* col     = (int*)carve((size_t)E * 4);
    float* mean  = (float*)carve((size_t)N * IN_CH * 4);
    float* h     = (float*)carve((size_t)N * IN_CH * 4);
    (void)ws_size; (void)n_in;

    float* out = (float*)d_out;
    (void)out_size;

    const int NB = (N + 1023) / 1024;  // scan blocks (98; must be <= 256)

    hipMemsetAsync(deg, 0, (size_t)N * 4, stream);
    k_count<<<(E + 255) / 256, 256, 0, stream>>>(dst, deg, E);
    k_scan1<<<NB, 256, 0, stream>>>(deg, row_ptr, bsums, N);
    k_scan2<<<1, 256, 0, stream>>>(bsums, NB);
    k_scan3<<<(N + 255) / 256, 256, 0, stream>>>(row_ptr, fill, bsums, N, E);
    k_scatter<<<(E + 255) / 256, 256, 0, stream>>>(src, dst, fill, col, E);

    // layer 1
    k_agg<<<(N + 3) / 4, 256, 0, stream>>>(row_ptr, col, x, mean, N);
    k_gemm<128><<<(N + 63) / 64, 256, 0, stream>>>(mean, x, Wl1, Wr1, bl1, h, N, 1);

    // layer 2
    k_agg<<<(N + 3) / 4, 256, 0, stream>>>(row_ptr, col, h, mean, N);
    k_gemm<64><<<(N + 63) / 64, 256, 0, stream>>>(mean, h, Wl2, Wr2, bl2, out, N, 0);
}